// Round 1
// baseline (931.287 us; speedup 1.0000x reference)
//
#include <hip/hip_runtime.h>
#include <math.h>

#define B_SZ 256
#define D_SZ 128
#define N_SZ 1000000
#define KP1  4097   // K+1

// Scores: out[b][k] = dot(memory[idx[b][k]], x[b]) / T
// One half-wave (32 lanes) per output element; each lane loads one float4
// (32 lanes * 16B = 512B = one full row, perfectly coalesced), then a
// 5-step shfl_xor reduction within the 32-lane group (masks <32 never
// cross the half-wave boundary on wave64).
__global__ void score_kernel(const float* __restrict__ x,
                             const float* __restrict__ memory,
                             const int* __restrict__ idx,
                             float* __restrict__ out) {
    const int b    = blockIdx.y;
    const int half = threadIdx.x >> 5;   // 0..7 half-wave id in a 256-thread block
    const int lane = threadIdx.x & 31;
    const float4 xv = reinterpret_cast<const float4*>(x + b * D_SZ)[lane];
    const float invT = 1.0f / 0.07f;
    for (int k = blockIdx.x * 8 + half; k < KP1; k += gridDim.x * 8) {
        const int row = idx[b * KP1 + k];
        const float4 mv = reinterpret_cast<const float4*>(memory + (size_t)row * D_SZ)[lane];
        float p = mv.x * xv.x + mv.y * xv.y + mv.z * xv.z + mv.w * xv.w;
        p += __shfl_xor(p, 16);
        p += __shfl_xor(p, 8);
        p += __shfl_xor(p, 4);
        p += __shfl_xor(p, 2);
        p += __shfl_xor(p, 1);
        if (lane == 0) out[b * KP1 + k] = p * invT;
    }
}

// Momentum update of the positive rows. One 128-thread block per batch row.
// Reads ORIGINAL memory (d_in), writes into the new_memory region of d_out
// (after the copy, enforced by stream ordering). np scatter semantics:
// for duplicate labels the last batch index wins.
__global__ void update_kernel(const float* __restrict__ x,
                              const float* __restrict__ memory,
                              const int* __restrict__ y,
                              float* __restrict__ new_memory) {
    const int b = blockIdx.x;
    const int d = threadIdx.x;           // 0..127
    const int row = y[b];
    bool last = true;
    for (int bp = b + 1; bp < B_SZ; ++bp) {
        if (y[bp] == row) last = false;  // uniform loop, y is tiny & cached
    }
    float w = 0.5f * memory[(size_t)row * D_SZ + d] + 0.5f * x[b * D_SZ + d];
    float s = w * w;
    // full-wave (64) butterfly, then combine the block's 2 waves via LDS
    s += __shfl_xor(s, 32);
    s += __shfl_xor(s, 16);
    s += __shfl_xor(s, 8);
    s += __shfl_xor(s, 4);
    s += __shfl_xor(s, 2);
    s += __shfl_xor(s, 1);
    __shared__ float part[2];
    if ((threadIdx.x & 63) == 0) part[threadIdx.x >> 6] = s;
    __syncthreads();
    const float inv = 1.0f / sqrtf(part[0] + part[1]);
    if (last) new_memory[(size_t)row * D_SZ + d] = w * inv;
}

extern "C" void kernel_launch(void* const* d_in, const int* in_sizes, int n_in,
                              void* d_out, int out_size, void* d_ws, size_t ws_size,
                              hipStream_t stream) {
    const float* x      = (const float*)d_in[0];
    const float* memory = (const float*)d_in[1];
    const int*   y      = (const int*)d_in[2];
    const int*   idx    = (const int*)d_in[3];

    float* out        = (float*)d_out;                  // [B, K+1]
    float* new_memory = out + (size_t)B_SZ * KP1;       // [N, D]

    // 1) new_memory starts as a copy of memory (512 MB d2d).
    hipMemcpyAsync(new_memory, memory, (size_t)N_SZ * D_SZ * sizeof(float),
                   hipMemcpyDeviceToDevice, stream);

    // 2) Scores from the ORIGINAL memory (gather happens before scatter).
    //    grid: 64 blocks over k * 256 batch rows; 8 half-waves per block.
    score_kernel<<<dim3(64, B_SZ), 256, 0, stream>>>(x, memory, idx, out);

    // 3) Momentum-update the 256 positive rows inside new_memory.
    update_kernel<<<B_SZ, D_SZ, 0, stream>>>(x, memory, y, new_memory);
}